// Round 5
// baseline (241.921 us; speedup 1.0000x reference)
//
#include <hip/hip_runtime.h>

// BioConvolution: 256 per-location GEMMs, C_l(64x128) = A_l(64x1024)*B_l(1024x128)+bias, ReLU
// X layout [n][h][w][ch] strides: n=262144, h=4096, w=64, ch=1.
// A_l[n][k] = X[n, r*4+i, c*4+j, ch], k = i*256+j*64+ch
//   -> offset = n*262144 + r*16384 + i*4096 + c*256 + j*64 + ch
// B_l[k][f] = Fw[l*131072 + k*128 + f]
//
// R5: barrier-free 4-wave workgroup. grid 256 (1 block per location, ~1 block/CU).
// Wave w owns f-slice [w*32, w*32+32) -> the 4 waves issue IDENTICAL A addresses
// (dedup'd in L1/L2 of the same CU) and ADJACENT 128B B chunks (dense streams).
// Unique request traffic ~210 MB vs R4's 402 MB. No __syncthreads anywhere;
// all ordering is wave-internal s_waitcnt. __launch_bounds__(256,1) keeps the
// prefetch rings (A depth-2, B depth-4, ~190 VGPR) live in registers
// (R4's VGPR=72 proved the compiler collapsed the pipeline at default occupancy).

typedef __bf16 bf16x8 __attribute__((ext_vector_type(8)));
typedef float f32x4 __attribute__((ext_vector_type(4)));

#define SBQ 36  // LDS B row stride in words (16 kp-rows per stage, +4 pad)

__device__ __forceinline__ unsigned pack2(float a, float b) {
  __bf16 lo = (__bf16)a, hi = (__bf16)b;
  return (unsigned)__builtin_bit_cast(unsigned short, lo) |
         ((unsigned)__builtin_bit_cast(unsigned short, hi) << 16);
}
__device__ __forceinline__ bf16x8 cvt8(float4 lo, float4 hi) {
  uint4 v;
  v.x = pack2(lo.x, lo.y);
  v.y = pack2(lo.z, lo.w);
  v.z = pack2(hi.x, hi.y);
  v.w = pack2(hi.z, hi.w);
  return __builtin_bit_cast(bf16x8, v);
}

__global__ __launch_bounds__(256, 1) void bioconv_wave4(
    const float* __restrict__ X, const float* __restrict__ Fw,
    const float* __restrict__ bias, float* __restrict__ out) {
  const int l = blockIdx.x;      // location 0..255
  const int r = l >> 4, c = l & 15;
  const int t = threadIdx.x;
  const int w = t >> 6;          // wave id -> f-slice [w*32, w*32+32)
  const int lane = t & 63;
  const int q = lane >> 4, nl = lane & 15;

  // 4 wave-private double-buffered B stages: 4 x 2 x 16 x SBQ words = 18432 B
  __shared__ __align__(16) unsigned Bs[4][2][16 * SBQ];

  // A row bases: row n = mb*16+nl; q*8 = k sub-offset within a 32-ch half-run.
  // Identical across the 4 waves -> L1-dedup'd.
  const float* pA[4];
#pragma unroll
  for (int mb = 0; mb < 4; ++mb)
    pA[mb] = X + (size_t)(mb * 16 + nl) * 262144 + r * 16384 + c * 256 + q * 8;

  // B: kp0 = lane>>3 (0..7), col chunk (lane&7)*4 within this wave's 32-col slice
  const float* pB = Fw + (size_t)l * 131072 + w * 32 + (lane >> 3) * 256 + (lane & 7) * 4;
  unsigned* const wpB = &Bs[w][0][0] + ((lane >> 3) * SBQ + (lane & 7) * 4);

  float4 aR[2][8];   // A prefetch ring, depth 2 (1 step = 8 float4/lane)
  float4 bR[4][4];   // B prefetch ring, depth 4 (1 step = 4 float4/lane)
  f32x4 acc[4][2];
#pragma unroll
  for (int mb = 0; mb < 4; ++mb) {
    acc[mb][0] = (f32x4){0.f, 0.f, 0.f, 0.f};
    acc[mb][1] = (f32x4){0.f, 0.f, 0.f, 0.f};
  }

  auto issueA = [&](int s, int ring) {
    const int p = s >> 1;  // pixel 0..15: i = p>>2, j = p&3
    const int off = (p >> 2) * 4096 + (p & 3) * 64 + (s & 1) * 32;
#pragma unroll
    for (int mb = 0; mb < 4; ++mb) {
      aR[ring][mb * 2] = *(const float4*)(pA[mb] + off);
      aR[ring][mb * 2 + 1] = *(const float4*)(pA[mb] + off + 4);
    }
  };
  auto issueB = [&](int s, int ring) {
#pragma unroll
    for (int rep = 0; rep < 2; ++rep) {
      const float* g = pB + s * 4096 + rep * 2048;
      bR[ring][rep * 2] = *(const float4*)(g);            // k = s*32 + 2*kp
      bR[ring][rep * 2 + 1] = *(const float4*)(g + 128);  // k odd
    }
  };
  auto writeB = [&](int s, int ring) {
    unsigned* wp = wpB + (s & 1) * (16 * SBQ);
#pragma unroll
    for (int rep = 0; rep < 2; ++rep) {
      float4 e0 = bR[ring][rep * 2], e1 = bR[ring][rep * 2 + 1];
      uint4 v;  // word = bf16 B[2kp][col] | bf16 B[2kp+1][col] << 16
      v.x = pack2(e0.x, e1.x);
      v.y = pack2(e0.y, e1.y);
      v.z = pack2(e0.z, e1.z);
      v.w = pack2(e0.w, e1.w);
      *(uint4*)(wp + rep * 8 * SBQ) = v;
    }
  };

  // ---- pipeline preamble ----
  issueA(0, 0);
  issueB(0, 0);
  issueA(1, 1);
  issueB(1, 1);
  issueB(2, 2);
  issueB(3, 3);
  writeB(0, 0);  // waits bR[0]; fills LDS buf 0

  // ---- 32 fully-unrolled K-steps (BK=32), no barriers ----
#pragma unroll
  for (int s = 0; s < 32; ++s) {
    if (s + 4 < 32) issueB(s + 4, (s + 4) & 3);
    if (s + 1 < 32) writeB(s + 1, (s + 1) & 3);  // -> buf[(s+1)&1]; wave-ordered vs reads

    bf16x8 af[4];
#pragma unroll
    for (int mb = 0; mb < 4; ++mb)
      af[mb] = cvt8(aR[s & 1][mb * 2], aR[s & 1][mb * 2 + 1]);  // waits aR[s&1]
    if (s + 2 < 32) issueA(s + 2, s & 1);

#pragma unroll
    for (int fb = 0; fb < 2; ++fb) {
      const unsigned* bp = &Bs[w][s & 1][(q * 4) * SBQ + fb * 16 + nl];
      uint4 v;
      v.x = bp[0];
      v.y = bp[SBQ];
      v.z = bp[2 * SBQ];
      v.w = bp[3 * SBQ];
      bf16x8 bfr = __builtin_bit_cast(bf16x8, v);
#pragma unroll
      for (int mb = 0; mb < 4; ++mb)
        acc[mb][fb] = __builtin_amdgcn_mfma_f32_16x16x32_bf16(af[mb], bfr, acc[mb][fb], 0, 0, 0);
    }
  }

  // ---- epilogue: bias + ReLU; D layout row = q*4+reg, col = nl ----
#pragma unroll
  for (int fb = 0; fb < 2; ++fb) {
    const int f = w * 32 + fb * 16 + nl;
    const float bv = bias[f];
    float* ob = out + (size_t)l * 128 + f;
#pragma unroll
    for (int mb = 0; mb < 4; ++mb) {
#pragma unroll
      for (int v = 0; v < 4; ++v) {
        const int row = mb * 16 + q * 4 + v;
        ob[(size_t)row * 32768] = fmaxf(acc[mb][fb][v] + bv, 0.f);
      }
    }
  }
}

extern "C" void kernel_launch(void* const* d_in, const int* in_sizes, int n_in,
                              void* d_out, int out_size, void* d_ws, size_t ws_size,
                              hipStream_t stream) {
  const float* X = (const float*)d_in[0];
  const float* Fw = (const float*)d_in[1];
  const float* bias = (const float*)d_in[2];
  float* out = (float*)d_out;
  bioconv_wave4<<<256, 256, 0, stream>>>(X, Fw, bias, out);
}